// Round 16
// baseline (405.246 us; speedup 1.0000x reference)
//
#include <hip/hip_runtime.h>
#include <math.h>

#define LSEQ 768
#define CS   384
#define CZ   128
#define NH   12
#define OUTD 2208
#define PROJW 1728   // [q 384 | k 384 | v 384 | qp 144 | kp 144 | vp 288]
#define LL2  (LSEQ*LSEQ)

__device__ __forceinline__ float waveSum(float v){
#pragma unroll
  for (int o = 32; o > 0; o >>= 1) v += __shfl_down(v, o, 64);
  return v;
}

// ---------------- LayerNorm + weight concat (merged) ----------------
__global__ __launch_bounds__(128) void k_lnwcat(
    const float* __restrict__ x, const float* __restrict__ g,
    const float* __restrict__ b, float* __restrict__ s,
    const float* __restrict__ Wq, const float* __restrict__ Wk,
    const float* __restrict__ Wv, const float* __restrict__ Wqp,
    const float* __restrict__ Wkp, const float* __restrict__ Wvp,
    const float* __restrict__ bqp, const float* __restrict__ bkp,
    const float* __restrict__ bvp,
    float* __restrict__ wcat, float* __restrict__ bcat){
  int blk = blockIdx.x, t = threadIdx.x;
  if (blk < LSEQ){
    int i = blk;
    const float* row = x + (size_t)i*CS;
    float v0 = row[t], v1 = row[t+128], v2 = row[t+256];
    float sum = v0+v1+v2;
    float sq  = v0*v0+v1*v1+v2*v2;
    float ws1 = waveSum(sum), ws2 = waveSum(sq);
    __shared__ float red[4];
    int w = t>>6, lane = t&63;
    if (lane == 0){ red[w] = ws1; red[w+2] = ws2; }
    __syncthreads();
    float mu   = (red[0]+red[1]) * (1.f/CS);
    float var  = (red[2]+red[3]) * (1.f/CS) - mu*mu;
    float rstd = rsqrtf(var + 1e-5f);
    float* o = s + (size_t)i*CS;
    o[t]     = (v0-mu)*rstd*g[t]     + b[t];
    o[t+128] = (v1-mu)*rstd*g[t+128] + b[t+128];
    o[t+256] = (v2-mu)*rstd*g[t+256] + b[t+256];
    return;
  }
  int idx = (blk - LSEQ)*128 + t;
  if (idx < PROJW){
    float bv = 0.f;
    if (idx >= 1440)      bv = bvp[idx-1440];
    else if (idx >= 1296) bv = bkp[idx-1296];
    else if (idx >= 1152) bv = bqp[idx-1152];
    bcat[idx] = bv;
  }
  if (idx >= 384*PROJW) return;
  int r = idx / PROJW, c = idx % PROJW;
  float v;
  if (c < 384)       v = Wq[r*384 + c];
  else if (c < 768)  v = Wk[r*384 + c-384];
  else if (c < 1152) v = Wv[r*384 + c-768];
  else if (c < 1296) v = Wqp[r*144 + c-1152];
  else if (c < 1440) v = Wkp[r*144 + c-1296];
  else               v = Wvp[r*288 + c-1440];
  wcat[idx] = v;
}

// ---------------- generic tiled GEMM (64x64, BK=16), aligned LDS (b128 reads) ----------------
__global__ __launch_bounds__(256) void k_gemm(
    const float* __restrict__ A, const float* __restrict__ B,
    const float* __restrict__ bias, float* __restrict__ C,
    int M, int N, int K, int kChunk){
  __shared__ float As[16][68];   // 68 floats = 272 B = 17x16 -> f4-aligned rows
  __shared__ float Bs[16][68];
  int j0 = blockIdx.x*64, i0 = blockIdx.y*64;
  int kBeg = blockIdx.z * kChunk;
  int t = threadIdx.x, tx = t & 15, ty = t >> 4;
  int arow = t >> 2, ak = (t & 3) * 4;
  int brow = t >> 4, bcol = (t & 15) * 4;
  float acc[4][4] = {};
  for (int kb = kBeg; kb < kBeg + kChunk; kb += 16){
    float4 av = *(const float4*)(A + (size_t)(i0+arow)*K + kb + ak);
    As[ak+0][arow]=av.x; As[ak+1][arow]=av.y; As[ak+2][arow]=av.z; As[ak+3][arow]=av.w;
    float4 bv = make_float4(0.f,0.f,0.f,0.f);
    if (j0 + bcol < N) bv = *(const float4*)(B + (size_t)(kb+brow)*N + j0 + bcol);
    *(float4*)(&Bs[brow][bcol]) = bv;
    __syncthreads();
#pragma unroll
    for (int kk = 0; kk < 16; ++kk){
      float a[4], b[4];
      *(float4*)a = *(const float4*)(&As[kk][ty*4]);
      *(float4*)b = *(const float4*)(&Bs[kk][tx*4]);
#pragma unroll
      for (int r = 0; r < 4; ++r)
#pragma unroll
        for (int c = 0; c < 4; ++c) acc[r][c] += a[r]*b[c];
    }
    __syncthreads();
  }
  bool noSplit = (gridDim.z == 1);
#pragma unroll
  for (int r = 0; r < 4; ++r){
    int i = i0 + ty*4 + r;
#pragma unroll
    for (int c = 0; c < 4; ++c){
      int j = j0 + tx*4 + c;
      if (j < N){
        float v = acc[r][c];
        if (noSplit && bias) v += bias[j];
        C[(size_t)i*N + j] = v;
      }
    }
  }
}

// ---------------- Wo GEMM: 128x128 tile, BK=8, 8x8 acc, split-K=12 ----------------
__global__ __launch_bounds__(256) void k_gemmWo(
    const float* __restrict__ A, const float* __restrict__ B, float* __restrict__ C){
  __shared__ float As[8][132];
  __shared__ float Bs[8][132];
  const int j0 = blockIdx.x*128, i0 = blockIdx.y*128;
  const int kBeg = blockIdx.z*184;
  const int t = threadIdx.x;
  const int arow = t >> 1, akq = (t & 1)*4;
  const int bk = t >> 5, bn = (t & 31)*4;
  const int tx = t & 15, ty = t >> 4;
  float acc[8][8] = {};
  for (int kb = kBeg; kb < kBeg+184; kb += 8){
    float4 av = *(const float4*)(A + (size_t)(i0+arow)*OUTD + kb + akq);
    float4 bv = *(const float4*)(B + (size_t)(kb+bk)*CS + j0 + bn);
    As[akq+0][arow]=av.x; As[akq+1][arow]=av.y; As[akq+2][arow]=av.z; As[akq+3][arow]=av.w;
    *(float4*)(&Bs[bk][bn]) = bv;
    __syncthreads();
#pragma unroll
    for (int k = 0; k < 8; ++k){
      float a[8], b[8];
      *(float4*)(a)   = *(const float4*)(&As[k][ty*8]);
      *(float4*)(a+4) = *(const float4*)(&As[k][ty*8+4]);
      *(float4*)(b)   = *(const float4*)(&Bs[k][tx*8]);
      *(float4*)(b+4) = *(const float4*)(&Bs[k][tx*8+4]);
#pragma unroll
      for (int r = 0; r < 8; ++r)
#pragma unroll
        for (int c = 0; c < 8; ++c) acc[r][c] += a[r]*b[c];
    }
    __syncthreads();
  }
  float* out = C + (size_t)blockIdx.z*LSEQ*CS;
#pragma unroll
  for (int r = 0; r < 8; ++r){
    float* o = out + (size_t)(i0+ty*8+r)*CS + j0 + tx*8;
    *(float4*)(o)   = make_float4(acc[r][0],acc[r][1],acc[r][2],acc[r][3]);
    *(float4*)(o+4) = make_float4(acc[r][4],acc[r][5],acc[r][6],acc[r][7]);
  }
}

// ---------------- prep: frames + Qa/Ka (K=44 pad 48) + norm biases ----------------
__global__ __launch_bounds__(256) void k_prep(
    float* __restrict__ proj, const float* __restrict__ rots,
    const float* __restrict__ trans, const float* __restrict__ hw,
    float* __restrict__ Qa, float* __restrict__ Ka, float* __restrict__ nrm){
  int i = blockIdx.x, t = threadIdx.x;
  __shared__ float wcl[12];
  __shared__ float qg[144], kg[144];
  if (t < 12) wcl[t] = log1pf(__expf(hw[t]));
  float* prow = proj + (size_t)i*PROJW;
  if (t < 192){
    const float* R  = rots + i*9;
    const float* tr = trans + i*3;
    int off = (t < 48) ? (1152 + t*3) : ((t < 96) ? (1296 + (t-48)*3) : (1440 + (t-96)*3));
    float x = prow[off], y = prow[off+1], z = prow[off+2];
    float gx = R[0]*x + R[1]*y + R[2]*z + tr[0];
    float gy = R[3]*x + R[4]*y + R[5]*z + tr[1];
    float gz = R[6]*x + R[7]*y + R[8]*z + tr[2];
    if (t < 48){ qg[t*3]=gx; qg[t*3+1]=gy; qg[t*3+2]=gz; }
    else if (t < 96){ int u=t-48; kg[u*3]=gx; kg[u*3+1]=gy; kg[u*3+2]=gz; }
    else { prow[off]=gx; prow[off+1]=gy; prow[off+2]=gz; }  // v_g in place
  }
  __syncthreads();
  const float isq = 0.17677669529663687f;
  for (int idx = t; idx < 576; idx += 256){
    int h = idx/48, d = idx%48;
    float qv = 0.f, kv = 0.f;
    if (d < 32){ qv = prow[h*32 + d]*isq; kv = prow[384 + h*32 + d]; }
    else if (d < 44){ qv = qg[h*12 + (d-32)]*wcl[h]; kv = kg[h*12 + (d-32)]; }
    Qa[((size_t)h*LSEQ + i)*48 + d] = qv;
    Ka[((size_t)h*LSEQ + i)*48 + d] = kv;
  }
  if (t < 24){
    int h = t % 12; int isK = (t >= 12) ? 1 : 0;
    const float* g = isK ? kg : qg;
    float sum = 0.f;
#pragma unroll
    for (int d = 0; d < 12; ++d){ float v = g[h*12+d]; sum += v*v; }
    nrm[((size_t)(isK*12 + h))*LSEQ + i] = -0.5f*wcl[h]*sum;
  }
}

// ---------------- fused: pairbias -> qk logits -> softmax -> out_pair; block per i ----------------
// v7: 768 threads (12 waves, 2 blk/CU). qk fused as phase 1.5: wave w computes head w's
// logits row from Qa (wave-uniform -> s_load) + Ka (L2-resident, shared by all blocks),
// adding into the LDS bias buffer. No logits tensor in HBM; attn holds probs only.
__global__ __launch_bounds__(768) void k_pairfused(
    const float* __restrict__ pair, const float* __restrict__ Wpb,
    const float* __restrict__ Qa, const float* __restrict__ Ka,
    const float* __restrict__ nrm,
    float* __restrict__ attn,   // [i][h][j]: probs out
    float* __restrict__ cat){
  const int i = blockIdx.x, t = threadIdx.x;          // t in [0,768)
  __shared__ __align__(16) float Sb[12*776];          // bias+logits -> probs -> red
  const float4* prowf4 = (const float4*)(pair + (size_t)i*LSEQ*CZ);
  const int w = t >> 6, lane = t & 63;                // 12 waves

  // ===== phase 1: pairbias; thread t = row t =====
  {
    const float4* src = prowf4 + (size_t)t*32;
    float acc[12] = {0.f,0.f,0.f,0.f,0.f,0.f,0.f,0.f,0.f,0.f,0.f,0.f};
#pragma unroll 2
    for (int c4 = 0; c4 < 32; ++c4){
      float4 pv = src[c4];
      const float* wq = Wpb + c4*48;   // wave-uniform -> scalar loads
#pragma unroll
      for (int h = 0; h < 12; ++h)
        acc[h] += pv.x*wq[h] + pv.y*wq[h+12] + pv.z*wq[h+24] + pv.w*wq[h+36];
    }
#pragma unroll
    for (int h = 0; h < 12; ++h) Sb[h*776 + t] = acc[h];
  }
  __syncthreads();

  // ===== phase 1.5: qk logits for head w, added into Sb (wave-local rows) =====
  {
    const int h = w;
    const float* qrow = Qa + ((size_t)h*LSEQ + i)*48;      // wave-uniform
    const float  nq   = nrm[(size_t)h*LSEQ + i];           // wave-uniform
    const float* nk   = nrm + (size_t)(12+h)*LSEQ;
#pragma unroll 1
    for (int jj = 0; jj < 12; ++jj){
      const int j = jj*64 + lane;
      const float4* krow = (const float4*)(Ka + ((size_t)h*LSEQ + j)*48);
      float s = 0.f;
#pragma unroll
      for (int c4 = 0; c4 < 12; ++c4){
        float4 kv = krow[c4];
        s += kv.x*qrow[c4*4] + kv.y*qrow[c4*4+1] + kv.z*qrow[c4*4+2] + kv.w*qrow[c4*4+3];
      }
      Sb[h*776 + j] += s + nq + nk[j];
    }
  }
  // no barrier needed: wave w wrote exactly head w's rows; phase 2 wave w reads them

  // ===== phase 2: softmax; wave w handles head w (from Sb only) =====
  {
    const int h = w;
    float* lg = attn + ((size_t)i*NH + h)*LSEQ;
    float4 xa = *(const float4*)(Sb + h*776 + lane*4);
    float4 xb = *(const float4*)(Sb + h*776 + 256 + lane*4);
    float4 xc = *(const float4*)(Sb + h*776 + 512 + lane*4);
    float m = fmaxf(fmaxf(fmaxf(xa.x,xa.y),fmaxf(xa.z,xa.w)),
             fmaxf(fmaxf(fmaxf(xb.x,xb.y),fmaxf(xb.z,xb.w)),
                   fmaxf(fmaxf(xc.x,xc.y),fmaxf(xc.z,xc.w))));
#pragma unroll
    for (int ms = 32; ms > 0; ms >>= 1) m = fmaxf(m, __shfl_xor(m, ms));
    xa.x=__expf(xa.x-m); xa.y=__expf(xa.y-m); xa.z=__expf(xa.z-m); xa.w=__expf(xa.w-m);
    xb.x=__expf(xb.x-m); xb.y=__expf(xb.y-m); xb.z=__expf(xb.z-m); xb.w=__expf(xb.w-m);
    xc.x=__expf(xc.x-m); xc.y=__expf(xc.y-m); xc.z=__expf(xc.z-m); xc.w=__expf(xc.w-m);
    float sm = xa.x+xa.y+xa.z+xa.w + xb.x+xb.y+xb.z+xb.w + xc.x+xc.y+xc.z+xc.w;
#pragma unroll
    for (int ms = 32; ms > 0; ms >>= 1) sm += __shfl_xor(sm, ms);
    float inv = 1.f/sm;
    xa.x*=inv; xa.y*=inv; xa.z*=inv; xa.w*=inv;
    xb.x*=inv; xb.y*=inv; xb.z*=inv; xb.w*=inv;
    xc.x*=inv; xc.y*=inv; xc.z*=inv; xc.w*=inv;
    *(float4*)(Sb + h*776 + lane*4)       = xa;
    *(float4*)(Sb + h*776 + 256 + lane*4) = xb;
    *(float4*)(Sb + h*776 + 512 + lane*4) = xc;
    *(float4*)(lg + lane*4)       = xa;
    *(float4*)(lg + 256 + lane*4) = xb;
    *(float4*)(lg + 512 + lane*4) = xc;
  }
  __syncthreads();

  // ===== phase 3: out_pair; 32 ch-quads x 24 row-groups =====
  const int cq = t & 31, rp = t >> 5;   // rp in [0,24)
  float4 acc3[12];
#pragma unroll
  for (int h = 0; h < 12; ++h) acc3[h] = make_float4(0.f,0.f,0.f,0.f);
#pragma unroll 2
  for (int g = 0; g < 8; ++g){
    const int r0 = g*96 + rp*4;
    float4 pv0 = prowf4[(size_t)(r0+0)*32 + cq];
    float4 pv1 = prowf4[(size_t)(r0+1)*32 + cq];
    float4 pv2 = prowf4[(size_t)(r0+2)*32 + cq];
    float4 pv3 = prowf4[(size_t)(r0+3)*32 + cq];
#pragma unroll
    for (int h = 0; h < 12; ++h){
      float4 p4 = *(const float4*)(Sb + h*776 + r0);
      acc3[h].x += pv0.x*p4.x + pv1.x*p4.y + pv2.x*p4.z + pv3.x*p4.w;
      acc3[h].y += pv0.y*p4.x + pv1.y*p4.y + pv2.y*p4.z + pv3.y*p4.w;
      acc3[h].z += pv0.z*p4.x + pv1.z*p4.y + pv2.z*p4.z + pv3.z*p4.w;
      acc3[h].w += pv0.w*p4.x + pv1.w*p4.y + pv2.w*p4.z + pv3.w*p4.w;
    }
  }
#pragma unroll
  for (int h = 0; h < 12; ++h){
    acc3[h].x += __shfl_xor(acc3[h].x, 32);
    acc3[h].y += __shfl_xor(acc3[h].y, 32);
    acc3[h].z += __shfl_xor(acc3[h].z, 32);
    acc3[h].w += __shfl_xor(acc3[h].w, 32);
  }
  __syncthreads();   // probs dead; reuse Sb[0..9216) as red[6][1536]
  if (w < 6 && lane < 32){
#pragma unroll
    for (int h = 0; h < 12; ++h)
      *(float4*)(Sb + w*1536 + h*128 + cq*4) = acc3[h];
  }
  __syncthreads();
  if (w >= 6 && lane < 32){
#pragma unroll
    for (int h = 0; h < 12; ++h){
      float4* d = (float4*)(Sb + (w-6)*1536 + h*128 + cq*4);
      float4 v = *d;
      v.x += acc3[h].x; v.y += acc3[h].y; v.z += acc3[h].z; v.w += acc3[h].w;
      *d = v;
    }
  }
  __syncthreads();
  float* crow = cat + (size_t)i*OUTD + 672;
#pragma unroll
  for (int o = t; o < 1536; o += 768)
    crow[o] = Sb[o] + Sb[1536+o] + Sb[3072+o] + Sb[4608+o] + Sb[6144+o] + Sb[7680+o];
}

// ---------------- PV GEMM (16-row tiles) + fused out-pts rotation ----------------
__global__ __launch_bounds__(256) void k_pv(
    const float* __restrict__ attn, const float* __restrict__ proj,
    const float* __restrict__ rots, const float* __restrict__ trans,
    float* __restrict__ cat){
  int h = blockIdx.y, i0 = blockIdx.x*16;
  __shared__ float As[32][17];   // [kk][row]
  __shared__ float Bs[32][60];   // 60 floats = 240 B = 15x16 -> f4-aligned rows
  __shared__ float pts[16][24];
  int t = threadIdx.x, tx = t & 15, ty = t >> 4;
  float acc[4] = {};
  for (int kb = 0; kb < LSEQ; kb += 32){
    __syncthreads();
    {
      int row = t >> 4, k2 = (t & 15)*2;
      float2 av = *(const float2*)(attn + ((size_t)(i0+row)*NH + h)*LSEQ + kb + k2);
      As[k2][row] = av.x; As[k2+1][row] = av.y;
    }
    for (int idx = t; idx < 32*56; idx += 256){
      int kk = idx/56, n = idx%56;
      const float* prow = proj + (size_t)(kb+kk)*PROJW;
      Bs[kk][n] = (n < 32) ? prow[768 + h*32 + n] : prow[1440 + h*24 + (n-32)];
    }
    __syncthreads();
    if (tx < 14){
#pragma unroll
      for (int kk = 0; kk < 32; ++kk){
        float a = As[kk][ty];
        float b[4]; *(float4*)b = *(const float4*)(&Bs[kk][tx*4]);
        acc[0] += a*b[0]; acc[1] += a*b[1]; acc[2] += a*b[2]; acc[3] += a*b[3];
      }
    }
  }
  __syncthreads();
  if (tx < 14){
    int i = i0 + ty;
#pragma unroll
    for (int c = 0; c < 4; ++c){
      int n = tx*4 + c;
      if (n < 32) cat[(size_t)i*OUTD + h*32 + n] = acc[c];
      else pts[ty][n-32] = acc[c];
    }
  }
  __syncthreads();
  if (t < 128){
    int row = t >> 3, p = t & 7;
    int i = i0 + row;
    const float* R = rots + i*9; const float* tr = trans + i*3;
    float x = pts[row][p*3]   - tr[0];
    float y = pts[row][p*3+1] - tr[1];
    float z = pts[row][p*3+2] - tr[2];
    float* o = cat + (size_t)i*OUTD + 384 + h*24 + p*3;
    o[0] = R[0]*x + R[3]*y + R[6]*z;
    o[1] = R[1]*x + R[4]*y + R[7]*z;
    o[2] = R[2]*x + R[5]*y + R[8]*z;
  }
}

// ---------------- split-K reduce + bias ----------------
__global__ __launch_bounds__(256) void k_reduce(
    const float* __restrict__ part, const float* __restrict__ bias,
    float* __restrict__ out){
  int idx = blockIdx.x*256 + threadIdx.x;
  if (idx >= LSEQ*CS) return;
  float v = bias[idx % CS];
#pragma unroll
  for (int z = 0; z < 12; ++z) v += part[(size_t)z*LSEQ*CS + idx];
  out[idx] = v;
}

extern "C" void kernel_launch(void* const* d_in, const int* in_sizes, int n_in,
                              void* d_out, int out_size, void* d_ws, size_t ws_size,
                              hipStream_t stream){
  const float* single = (const float*)d_in[0];
  const float* pair   = (const float*)d_in[1];
  const float* rots   = (const float*)d_in[2];
  const float* trans  = (const float*)d_in[3];
  const float* ln_g   = (const float*)d_in[4];
  const float* ln_b   = (const float*)d_in[5];
  const float* Wq  = (const float*)d_in[6];
  const float* Wk  = (const float*)d_in[7];
  const float* Wv  = (const float*)d_in[8];
  const float* Wqp = (const float*)d_in[9];
  const float* bqp = (const float*)d_in[10];
  const float* Wkp = (const float*)d_in[11];
  const float* bkp = (const float*)d_in[12];
  const float* Wvp = (const float*)d_in[13];
  const float* bvp = (const float*)d_in[14];
  const float* Wpb = (const float*)d_in[15];
  const float* hw  = (const float*)d_in[16];
  const float* Wo  = (const float*)d_in[17];
  const float* bo  = (const float*)d_in[18];
  float* out = (float*)d_out;

  float* ws = (float*)d_ws;
  float* s    = ws;                  // 294912
  float* wcat = ws + 294912;         // 663552
  float* bcat = ws + 958464;         // 1792
  float* Qa   = ws + 960256;         // 442368
  float* Ka   = ws + 1402624;        // 442368
  float* nrm  = ws + 1844992;        // 18432
  float* proj = ws + 1863424;        // 1327104
  float* attn = ws + 3190528;        // 7077888 [i][h][j] probs
  float* cat  = ws + 10268416;       // 1695744
  float* part = attn;                // 12*294912 = 3538944 (attn dead after pv)

  int wcatBlocks = (384*PROJW + 127)/128;
  k_lnwcat<<<LSEQ + wcatBlocks, 128, 0, stream>>>(single, ln_g, ln_b, s,
      Wq, Wk, Wv, Wqp, Wkp, Wvp, bqp, bkp, bvp, wcat, bcat);
  k_gemm<<<dim3(27,12,1), 256, 0, stream>>>(s, wcat, bcat, proj, 768, PROJW, 384, 384);
  k_prep<<<LSEQ, 256, 0, stream>>>(proj, rots, trans, hw, Qa, Ka, nrm);
  k_pairfused<<<LSEQ, 768, 0, stream>>>(pair, Wpb, Qa, Ka, nrm, attn, cat);
  k_pv<<<dim3(48, NH), 256, 0, stream>>>(attn, proj, rots, trans, cat);
  k_gemmWo<<<dim3(3,6,12), 256, 0, stream>>>(cat, Wo, part);
  k_reduce<<<(LSEQ*CS+255)/256, 256, 0, stream>>>(part, bo, out);
}

// Round 17
// 330.943 us; speedup vs baseline: 1.2245x; 1.2245x over previous
//
#include <hip/hip_runtime.h>
#include <math.h>

#define LSEQ 768
#define CS   384
#define CZ   128
#define NH   12
#define OUTD 2208
#define PROJW 1728   // [q 384 | k 384 | v 384 | qp 144 | kp 144 | vp 288]
#define LL2  (LSEQ*LSEQ)

__device__ __forceinline__ float waveSum(float v){
#pragma unroll
  for (int o = 32; o > 0; o >>= 1) v += __shfl_down(v, o, 64);
  return v;
}

// ---------------- LayerNorm + weight concat (merged) ----------------
__global__ __launch_bounds__(128) void k_lnwcat(
    const float* __restrict__ x, const float* __restrict__ g,
    const float* __restrict__ b, float* __restrict__ s,
    const float* __restrict__ Wq, const float* __restrict__ Wk,
    const float* __restrict__ Wv, const float* __restrict__ Wqp,
    const float* __restrict__ Wkp, const float* __restrict__ Wvp,
    const float* __restrict__ bqp, const float* __restrict__ bkp,
    const float* __restrict__ bvp,
    float* __restrict__ wcat, float* __restrict__ bcat){
  int blk = blockIdx.x, t = threadIdx.x;
  if (blk < LSEQ){
    int i = blk;
    const float* row = x + (size_t)i*CS;
    float v0 = row[t], v1 = row[t+128], v2 = row[t+256];
    float sum = v0+v1+v2;
    float sq  = v0*v0+v1*v1+v2*v2;
    float ws1 = waveSum(sum), ws2 = waveSum(sq);
    __shared__ float red[4];
    int w = t>>6, lane = t&63;
    if (lane == 0){ red[w] = ws1; red[w+2] = ws2; }
    __syncthreads();
    float mu   = (red[0]+red[1]) * (1.f/CS);
    float var  = (red[2]+red[3]) * (1.f/CS) - mu*mu;
    float rstd = rsqrtf(var + 1e-5f);
    float* o = s + (size_t)i*CS;
    o[t]     = (v0-mu)*rstd*g[t]     + b[t];
    o[t+128] = (v1-mu)*rstd*g[t+128] + b[t+128];
    o[t+256] = (v2-mu)*rstd*g[t+256] + b[t+256];
    return;
  }
  int idx = (blk - LSEQ)*128 + t;
  if (idx < PROJW){
    float bv = 0.f;
    if (idx >= 1440)      bv = bvp[idx-1440];
    else if (idx >= 1296) bv = bkp[idx-1296];
    else if (idx >= 1152) bv = bqp[idx-1152];
    bcat[idx] = bv;
  }
  if (idx >= 384*PROJW) return;
  int r = idx / PROJW, c = idx % PROJW;
  float v;
  if (c < 384)       v = Wq[r*384 + c];
  else if (c < 768)  v = Wk[r*384 + c-384];
  else if (c < 1152) v = Wv[r*384 + c-768];
  else if (c < 1296) v = Wqp[r*144 + c-1152];
  else if (c < 1440) v = Wkp[r*144 + c-1296];
  else               v = Wvp[r*288 + c-1440];
  wcat[idx] = v;
}

// ---------------- generic tiled GEMM (64x64, BK=16), aligned LDS (b128 reads) ----------------
__global__ __launch_bounds__(256) void k_gemm(
    const float* __restrict__ A, const float* __restrict__ B,
    const float* __restrict__ bias, float* __restrict__ C,
    int M, int N, int K, int kChunk){
  __shared__ float As[16][68];   // 68 floats = 272 B = 17x16 -> f4-aligned rows
  __shared__ float Bs[16][68];
  int j0 = blockIdx.x*64, i0 = blockIdx.y*64;
  int kBeg = blockIdx.z * kChunk;
  int t = threadIdx.x, tx = t & 15, ty = t >> 4;
  int arow = t >> 2, ak = (t & 3) * 4;
  int brow = t >> 4, bcol = (t & 15) * 4;
  float acc[4][4] = {};
  for (int kb = kBeg; kb < kBeg + kChunk; kb += 16){
    float4 av = *(const float4*)(A + (size_t)(i0+arow)*K + kb + ak);
    As[ak+0][arow]=av.x; As[ak+1][arow]=av.y; As[ak+2][arow]=av.z; As[ak+3][arow]=av.w;
    float4 bv = make_float4(0.f,0.f,0.f,0.f);
    if (j0 + bcol < N) bv = *(const float4*)(B + (size_t)(kb+brow)*N + j0 + bcol);
    *(float4*)(&Bs[brow][bcol]) = bv;
    __syncthreads();
#pragma unroll
    for (int kk = 0; kk < 16; ++kk){
      float a[4], b[4];
      *(float4*)a = *(const float4*)(&As[kk][ty*4]);
      *(float4*)b = *(const float4*)(&Bs[kk][tx*4]);
#pragma unroll
      for (int r = 0; r < 4; ++r)
#pragma unroll
        for (int c = 0; c < 4; ++c) acc[r][c] += a[r]*b[c];
    }
    __syncthreads();
  }
  bool noSplit = (gridDim.z == 1);
#pragma unroll
  for (int r = 0; r < 4; ++r){
    int i = i0 + ty*4 + r;
#pragma unroll
    for (int c = 0; c < 4; ++c){
      int j = j0 + tx*4 + c;
      if (j < N){
        float v = acc[r][c];
        if (noSplit && bias) v += bias[j];
        C[(size_t)i*N + j] = v;
      }
    }
  }
}

// ---------------- Wo GEMM: 128x128 tile, BK=8, 8x8 acc, split-K=12 ----------------
__global__ __launch_bounds__(256) void k_gemmWo(
    const float* __restrict__ A, const float* __restrict__ B, float* __restrict__ C){
  __shared__ float As[8][132];
  __shared__ float Bs[8][132];
  const int j0 = blockIdx.x*128, i0 = blockIdx.y*128;
  const int kBeg = blockIdx.z*184;
  const int t = threadIdx.x;
  const int arow = t >> 1, akq = (t & 1)*4;
  const int bk = t >> 5, bn = (t & 31)*4;
  const int tx = t & 15, ty = t >> 4;
  float acc[8][8] = {};
  for (int kb = kBeg; kb < kBeg+184; kb += 8){
    float4 av = *(const float4*)(A + (size_t)(i0+arow)*OUTD + kb + akq);
    float4 bv = *(const float4*)(B + (size_t)(kb+bk)*CS + j0 + bn);
    As[akq+0][arow]=av.x; As[akq+1][arow]=av.y; As[akq+2][arow]=av.z; As[akq+3][arow]=av.w;
    *(float4*)(&Bs[bk][bn]) = bv;
    __syncthreads();
#pragma unroll
    for (int k = 0; k < 8; ++k){
      float a[8], b[8];
      *(float4*)(a)   = *(const float4*)(&As[k][ty*8]);
      *(float4*)(a+4) = *(const float4*)(&As[k][ty*8+4]);
      *(float4*)(b)   = *(const float4*)(&Bs[k][tx*8]);
      *(float4*)(b+4) = *(const float4*)(&Bs[k][tx*8+4]);
#pragma unroll
      for (int r = 0; r < 8; ++r)
#pragma unroll
        for (int c = 0; c < 8; ++c) acc[r][c] += a[r]*b[c];
    }
    __syncthreads();
  }
  float* out = C + (size_t)blockIdx.z*LSEQ*CS;
#pragma unroll
  for (int r = 0; r < 8; ++r){
    float* o = out + (size_t)(i0+ty*8+r)*CS + j0 + tx*8;
    *(float4*)(o)   = make_float4(acc[r][0],acc[r][1],acc[r][2],acc[r][3]);
    *(float4*)(o+4) = make_float4(acc[r][4],acc[r][5],acc[r][6],acc[r][7]);
  }
}

// ---------------- prep: frames + Qa/Ka (K=44 pad 48) + norm biases ----------------
__global__ __launch_bounds__(256) void k_prep(
    float* __restrict__ proj, const float* __restrict__ rots,
    const float* __restrict__ trans, const float* __restrict__ hw,
    float* __restrict__ Qa, float* __restrict__ Ka, float* __restrict__ nrm){
  int i = blockIdx.x, t = threadIdx.x;
  __shared__ float wcl[12];
  __shared__ float qg[144], kg[144];
  if (t < 12) wcl[t] = log1pf(__expf(hw[t]));
  float* prow = proj + (size_t)i*PROJW;
  if (t < 192){
    const float* R  = rots + i*9;
    const float* tr = trans + i*3;
    int off = (t < 48) ? (1152 + t*3) : ((t < 96) ? (1296 + (t-48)*3) : (1440 + (t-96)*3));
    float x = prow[off], y = prow[off+1], z = prow[off+2];
    float gx = R[0]*x + R[1]*y + R[2]*z + tr[0];
    float gy = R[3]*x + R[4]*y + R[5]*z + tr[1];
    float gz = R[6]*x + R[7]*y + R[8]*z + tr[2];
    if (t < 48){ qg[t*3]=gx; qg[t*3+1]=gy; qg[t*3+2]=gz; }
    else if (t < 96){ int u=t-48; kg[u*3]=gx; kg[u*3+1]=gy; kg[u*3+2]=gz; }
    else { prow[off]=gx; prow[off+1]=gy; prow[off+2]=gz; }  // v_g in place
  }
  __syncthreads();
  const float isq = 0.17677669529663687f;
  for (int idx = t; idx < 576; idx += 256){
    int h = idx/48, d = idx%48;
    float qv = 0.f, kv = 0.f;
    if (d < 32){ qv = prow[h*32 + d]*isq; kv = prow[384 + h*32 + d]; }
    else if (d < 44){ qv = qg[h*12 + (d-32)]*wcl[h]; kv = kg[h*12 + (d-32)]; }
    Qa[((size_t)h*LSEQ + i)*48 + d] = qv;
    Ka[((size_t)h*LSEQ + i)*48 + d] = kv;
  }
  if (t < 24){
    int h = t % 12; int isK = (t >= 12) ? 1 : 0;
    const float* g = isK ? kg : qg;
    float sum = 0.f;
#pragma unroll
    for (int d = 0; d < 12; ++d){ float v = g[h*12+d]; sum += v*v; }
    nrm[((size_t)(isK*12 + h))*LSEQ + i] = -0.5f*wcl[h]*sum;
  }
}

// ---------------- logits GEMM -> attn[i][h][j]; transposed LDS, b128 reads ----------------
__global__ __launch_bounds__(256) void k_qkaug(
    const float* __restrict__ Qa, const float* __restrict__ Ka,
    const float* __restrict__ nrm, float* __restrict__ logits){
  int j0 = blockIdx.x*64, i0 = blockIdx.y*64, h = blockIdx.z;
  __shared__ float Qs[48][68], Ks[48][68];  // [k][row], 68-pad -> aligned f4 rows
  __shared__ float nq[64], nk[64];
  int t = threadIdx.x;
  for (int idx = t; idx < 768; idx += 256){
    int row = idx/12, c4 = (idx%12)*4;
    float4 qv = *(const float4*)(Qa + ((size_t)h*LSEQ + i0+row)*48 + c4);
    Qs[c4+0][row]=qv.x; Qs[c4+1][row]=qv.y; Qs[c4+2][row]=qv.z; Qs[c4+3][row]=qv.w;
    float4 kv = *(const float4*)(Ka + ((size_t)h*LSEQ + j0+row)*48 + c4);
    Ks[c4+0][row]=kv.x; Ks[c4+1][row]=kv.y; Ks[c4+2][row]=kv.z; Ks[c4+3][row]=kv.w;
  }
  if (t < 64) nq[t] = nrm[(size_t)h*LSEQ + i0 + t];
  else if (t < 128) nk[t-64] = nrm[(size_t)(12+h)*LSEQ + j0 + (t-64)];
  __syncthreads();
  int tx = t & 15, ty = t >> 4;
  float acc[4][4] = {};
#pragma unroll 4
  for (int k = 0; k < 44; ++k){
    float a[4], b[4];
    *(float4*)a = *(const float4*)(&Qs[k][ty*4]);
    *(float4*)b = *(const float4*)(&Ks[k][tx*4]);
#pragma unroll
    for (int r = 0; r < 4; ++r)
#pragma unroll
      for (int c = 0; c < 4; ++c) acc[r][c] += a[r]*b[c];
  }
  float nqa[4] = {nq[ty*4], nq[ty*4+1], nq[ty*4+2], nq[ty*4+3]};
  float nk0=nk[tx*4], nk1=nk[tx*4+1], nk2=nk[tx*4+2], nk3=nk[tx*4+3];
#pragma unroll
  for (int r = 0; r < 4; ++r){
    float4 o = make_float4(acc[r][0]+nqa[r]+nk0, acc[r][1]+nqa[r]+nk1,
                           acc[r][2]+nqa[r]+nk2, acc[r][3]+nqa[r]+nk3);
    *(float4*)(logits + ((size_t)(i0+ty*4+r)*NH + h)*LSEQ + j0 + tx*4) = o;
  }
}

// ---------------- fused: pairbias -> softmax -> out_pair; block per i ----------------
// v8 = R15 structure + phase-1 explicit 4-line batching (VGPR max set by phase 3, safe).
__global__ __launch_bounds__(768, 6) void k_pairfused(
    const float* __restrict__ pair, const float* __restrict__ Wpb,
    float* __restrict__ attn,   // [i][h][j]: logits in -> normalized probs out
    float* __restrict__ cat){
  const int i = blockIdx.x, t = threadIdx.x;          // t in [0,768)
  __shared__ __align__(16) float Sb[12*776];          // bias -> probs -> epilogue red
  const float4* prowf4 = (const float4*)(pair + (size_t)i*LSEQ*CZ);
  const int w = t >> 6, lane = t & 63;                // 12 waves

  // ===== phase 1: pairbias; thread t = row t; 4 independent loads in flight =====
  {
    const float4* src = prowf4 + (size_t)t*32;
    float acc[12] = {0.f,0.f,0.f,0.f,0.f,0.f,0.f,0.f,0.f,0.f,0.f,0.f};
#pragma unroll 1
    for (int gl = 0; gl < 8; ++gl){
      float4 p0 = src[gl*4+0];
      float4 p1 = src[gl*4+1];
      float4 p2 = src[gl*4+2];
      float4 p3 = src[gl*4+3];
      const float* wq = Wpb + gl*192;   // wave-uniform -> scalar loads
#pragma unroll
      for (int h = 0; h < 12; ++h){
        acc[h] += p0.x*wq[h]     + p0.y*wq[h+12]  + p0.z*wq[h+24]  + p0.w*wq[h+36]
                + p1.x*wq[h+48]  + p1.y*wq[h+60]  + p1.z*wq[h+72]  + p1.w*wq[h+84]
                + p2.x*wq[h+96]  + p2.y*wq[h+108] + p2.z*wq[h+120] + p2.w*wq[h+132]
                + p3.x*wq[h+144] + p3.y*wq[h+156] + p3.z*wq[h+168] + p3.w*wq[h+180];
      }
    }
#pragma unroll
    for (int h = 0; h < 12; ++h) Sb[h*776 + t] = acc[h];
  }
  __syncthreads();

  // ===== phase 2: softmax; wave w handles head w =====
  {
    const int h = w;
    float* lg = attn + ((size_t)i*NH + h)*LSEQ;
    float4 xa = *(const float4*)(lg + lane*4);
    float4 xb = *(const float4*)(lg + 256 + lane*4);
    float4 xc = *(const float4*)(lg + 512 + lane*4);
    float4 ba = *(const float4*)(Sb + h*776 + lane*4);
    float4 bb = *(const float4*)(Sb + h*776 + 256 + lane*4);
    float4 bc = *(const float4*)(Sb + h*776 + 512 + lane*4);
    xa.x+=ba.x; xa.y+=ba.y; xa.z+=ba.z; xa.w+=ba.w;
    xb.x+=bb.x; xb.y+=bb.y; xb.z+=bb.z; xb.w+=bb.w;
    xc.x+=bc.x; xc.y+=bc.y; xc.z+=bc.z; xc.w+=bc.w;
    float m = fmaxf(fmaxf(fmaxf(xa.x,xa.y),fmaxf(xa.z,xa.w)),
             fmaxf(fmaxf(fmaxf(xb.x,xb.y),fmaxf(xb.z,xb.w)),
                   fmaxf(fmaxf(xc.x,xc.y),fmaxf(xc.z,xc.w))));
#pragma unroll
    for (int ms = 32; ms > 0; ms >>= 1) m = fmaxf(m, __shfl_xor(m, ms));
    xa.x=__expf(xa.x-m); xa.y=__expf(xa.y-m); xa.z=__expf(xa.z-m); xa.w=__expf(xa.w-m);
    xb.x=__expf(xb.x-m); xb.y=__expf(xb.y-m); xb.z=__expf(xb.z-m); xb.w=__expf(xb.w-m);
    xc.x=__expf(xc.x-m); xc.y=__expf(xc.y-m); xc.z=__expf(xc.z-m); xc.w=__expf(xc.w-m);
    float sm = xa.x+xa.y+xa.z+xa.w + xb.x+xb.y+xb.z+xb.w + xc.x+xc.y+xc.z+xc.w;
#pragma unroll
    for (int ms = 32; ms > 0; ms >>= 1) sm += __shfl_xor(sm, ms);
    float inv = 1.f/sm;
    xa.x*=inv; xa.y*=inv; xa.z*=inv; xa.w*=inv;
    xb.x*=inv; xb.y*=inv; xb.z*=inv; xb.w*=inv;
    xc.x*=inv; xc.y*=inv; xc.z*=inv; xc.w*=inv;
    *(float4*)(Sb + h*776 + lane*4)       = xa;
    *(float4*)(Sb + h*776 + 256 + lane*4) = xb;
    *(float4*)(Sb + h*776 + 512 + lane*4) = xc;
    *(float4*)(lg + lane*4)       = xa;
    *(float4*)(lg + 256 + lane*4) = xb;
    *(float4*)(lg + 512 + lane*4) = xc;
  }
  __syncthreads();

  // ===== phase 3: out_pair; 32 ch-quads x 24 row-groups =====
  const int cq = t & 31, rp = t >> 5;   // rp in [0,24)
  float4 acc3[12];
#pragma unroll
  for (int h = 0; h < 12; ++h) acc3[h] = make_float4(0.f,0.f,0.f,0.f);
#pragma unroll 2
  for (int g = 0; g < 8; ++g){
    const int r0 = g*96 + rp*4;
    float4 pv0 = prowf4[(size_t)(r0+0)*32 + cq];
    float4 pv1 = prowf4[(size_t)(r0+1)*32 + cq];
    float4 pv2 = prowf4[(size_t)(r0+2)*32 + cq];
    float4 pv3 = prowf4[(size_t)(r0+3)*32 + cq];
#pragma unroll
    for (int h = 0; h < 12; ++h){
      float4 p4 = *(const float4*)(Sb + h*776 + r0);
      acc3[h].x += pv0.x*p4.x + pv1.x*p4.y + pv2.x*p4.z + pv3.x*p4.w;
      acc3[h].y += pv0.y*p4.x + pv1.y*p4.y + pv2.y*p4.z + pv3.y*p4.w;
      acc3[h].z += pv0.z*p4.x + pv1.z*p4.y + pv2.z*p4.z + pv3.z*p4.w;
      acc3[h].w += pv0.w*p4.x + pv1.w*p4.y + pv2.w*p4.z + pv3.w*p4.w;
    }
  }
#pragma unroll
  for (int h = 0; h < 12; ++h){
    acc3[h].x += __shfl_xor(acc3[h].x, 32);
    acc3[h].y += __shfl_xor(acc3[h].y, 32);
    acc3[h].z += __shfl_xor(acc3[h].z, 32);
    acc3[h].w += __shfl_xor(acc3[h].w, 32);
  }
  __syncthreads();   // probs dead; reuse Sb[0..9216) as red[6][1536]
  if (w < 6 && lane < 32){
#pragma unroll
    for (int h = 0; h < 12; ++h)
      *(float4*)(Sb + w*1536 + h*128 + cq*4) = acc3[h];
  }
  __syncthreads();
  if (w >= 6 && lane < 32){
#pragma unroll
    for (int h = 0; h < 12; ++h){
      float4* d = (float4*)(Sb + (w-6)*1536 + h*128 + cq*4);
      float4 v = *d;
      v.x += acc3[h].x; v.y += acc3[h].y; v.z += acc3[h].z; v.w += acc3[h].w;
      *d = v;
    }
  }
  __syncthreads();
  float* crow = cat + (size_t)i*OUTD + 672;
#pragma unroll
  for (int o = t; o < 1536; o += 768)
    crow[o] = Sb[o] + Sb[1536+o] + Sb[3072+o] + Sb[4608+o] + Sb[6144+o] + Sb[7680+o];
}

// ---------------- PV GEMM (16-row tiles) + fused out-pts rotation ----------------
__global__ __launch_bounds__(256) void k_pv(
    const float* __restrict__ attn, const float* __restrict__ proj,
    const float* __restrict__ rots, const float* __restrict__ trans,
    float* __restrict__ cat){
  int h = blockIdx.y, i0 = blockIdx.x*16;
  __shared__ float As[32][17];   // [kk][row]
  __shared__ float Bs[32][60];   // 60 floats = 240 B = 15x16 -> f4-aligned rows
  __shared__ float pts[16][24];
  int t = threadIdx.x, tx = t & 15, ty = t >> 4;
  float acc[4] = {};
  for (int kb = 0; kb < LSEQ; kb += 32){
    __syncthreads();
    {
      int row = t >> 4, k2 = (t & 15)*2;
      float2 av = *(const float2*)(attn + ((size_t)(i0+row)*NH + h)*LSEQ + kb + k2);
      As[k2][row] = av.x; As[k2+1][row] = av.y;
    }
    for (int idx = t; idx < 32*56; idx += 256){
      int kk = idx/56, n = idx%56;
      const float* prow = proj + (size_t)(kb+kk)*PROJW;
      Bs[kk][n] = (n < 32) ? prow[768 + h*32 + n] : prow[1440 + h*24 + (n-32)];
    }
    __syncthreads();
    if (tx < 14){
#pragma unroll
      for (int kk = 0; kk < 32; ++kk){
        float a = As[kk][ty];
        float b[4]; *(float4*)b = *(const float4*)(&Bs[kk][tx*4]);
        acc[0] += a*b[0]; acc[1] += a*b[1]; acc[2] += a*b[2]; acc[3] += a*b[3];
      }
    }
  }
  __syncthreads();
  if (tx < 14){
    int i = i0 + ty;
#pragma unroll
    for (int c = 0; c < 4; ++c){
      int n = tx*4 + c;
      if (n < 32) cat[(size_t)i*OUTD + h*32 + n] = acc[c];
      else pts[ty][n-32] = acc[c];
    }
  }
  __syncthreads();
  if (t < 128){
    int row = t >> 3, p = t & 7;
    int i = i0 + row;
    const float* R = rots + i*9; const float* tr = trans + i*3;
    float x = pts[row][p*3]   - tr[0];
    float y = pts[row][p*3+1] - tr[1];
    float z = pts[row][p*3+2] - tr[2];
    float* o = cat + (size_t)i*OUTD + 384 + h*24 + p*3;
    o[0] = R[0]*x + R[3]*y + R[6]*z;
    o[1] = R[1]*x + R[4]*y + R[7]*z;
    o[2] = R[2]*x + R[5]*y + R[8]*z;
  }
}

// ---------------- split-K reduce + bias ----------------
__global__ __launch_bounds__(256) void k_reduce(
    const float* __restrict__ part, const float* __restrict__ bias,
    float* __restrict__ out){
  int idx = blockIdx.x*256 + threadIdx.x;
  if (idx >= LSEQ*CS) return;
  float v = bias[idx % CS];
#pragma unroll
  for (int z = 0; z < 12; ++z) v += part[(size_t)z*LSEQ*CS + idx];
  out[idx] = v;
}

extern "C" void kernel_launch(void* const* d_in, const int* in_sizes, int n_in,
                              void* d_out, int out_size, void* d_ws, size_t ws_size,
                              hipStream_t stream){
  const float* single = (const float*)d_in[0];
  const float* pair   = (const float*)d_in[1];
  const float* rots   = (const float*)d_in[2];
  const float* trans  = (const float*)d_in[3];
  const float* ln_g   = (const float*)d_in[4];
  const float* ln_b   = (const float*)d_in[5];
  const float* Wq  = (const float*)d_in[6];
  const float* Wk  = (const float*)d_in[7];
  const float* Wv  = (const float*)d_in[8];
  const float* Wqp = (const float*)d_in[9];
  const float* bqp = (const float*)d_in[10];
  const float* Wkp = (const float*)d_in[11];
  const float* bkp = (const float*)d_in[12];
  const float* Wvp = (const float*)d_in[13];
  const float* bvp = (const float*)d_in[14];
  const float* Wpb = (const float*)d_in[15];
  const float* hw  = (const float*)d_in[16];
  const float* Wo  = (const float*)d_in[17];
  const float* bo  = (const float*)d_in[18];
  float* out = (float*)d_out;

  float* ws = (float*)d_ws;
  float* s    = ws;                  // 294912
  float* wcat = ws + 294912;         // 663552
  float* bcat = ws + 958464;         // 1792
  float* Qa   = ws;                  // overlays s/wcat after proj GEMM
  float* Ka   = ws + 442368;
  float* nrm  = ws + 884736;
  float* proj = ws + 960256;         // 1327104
  float* attn = ws + 2287360;        // 7077888 [i][h][j] (logits -> probs in place)
  float* cat  = ws + 9365248;        // 1695744
  float* part = attn;                // 12*294912 = 3538944 (attn dead after pv)

  int wcatBlocks = (384*PROJW + 127)/128;
  k_lnwcat<<<LSEQ + wcatBlocks, 128, 0, stream>>>(single, ln_g, ln_b, s,
      Wq, Wk, Wv, Wqp, Wkp, Wvp, bqp, bkp, bvp, wcat, bcat);
  k_gemm<<<dim3(27,12,1), 256, 0, stream>>>(s, wcat, bcat, proj, 768, PROJW, 384, 384);
  k_prep<<<LSEQ, 256, 0, stream>>>(proj, rots, trans, hw, Qa, Ka, nrm);
  k_qkaug<<<dim3(12,12,12), 256, 0, stream>>>(Qa, Ka, nrm, attn);
  k_pairfused<<<LSEQ, 768, 0, stream>>>(pair, Wpb, attn, cat);
  k_pv<<<dim3(48, NH), 256, 0, stream>>>(attn, proj, rots, trans, cat);
  k_gemmWo<<<dim3(3,6,12), 256, 0, stream>>>(cat, Wo, part);
  k_reduce<<<(LSEQ*CS+255)/256, 256, 0, stream>>>(part, bo, out);
}

// Round 18
// 317.789 us; speedup vs baseline: 1.2752x; 1.0414x over previous
//
#include <hip/hip_runtime.h>
#include <math.h>

#define LSEQ 768
#define CS   384
#define CZ   128
#define NH   12
#define OUTD 2208
#define PROJW 1728   // [q 384 | k 384 | v 384 | qp 144 | kp 144 | vp 288]
#define LL2  (LSEQ*LSEQ)

__device__ __forceinline__ float waveSum(float v){
#pragma unroll
  for (int o = 32; o > 0; o >>= 1) v += __shfl_down(v, o, 64);
  return v;
}

// ---------------- LayerNorm + weight concat (merged) ----------------
__global__ __launch_bounds__(128) void k_lnwcat(
    const float* __restrict__ x, const float* __restrict__ g,
    const float* __restrict__ b, float* __restrict__ s,
    const float* __restrict__ Wq, const float* __restrict__ Wk,
    const float* __restrict__ Wv, const float* __restrict__ Wqp,
    const float* __restrict__ Wkp, const float* __restrict__ Wvp,
    const float* __restrict__ bqp, const float* __restrict__ bkp,
    const float* __restrict__ bvp,
    float* __restrict__ wcat, float* __restrict__ bcat){
  int blk = blockIdx.x, t = threadIdx.x;
  if (blk < LSEQ){
    int i = blk;
    const float* row = x + (size_t)i*CS;
    float v0 = row[t], v1 = row[t+128], v2 = row[t+256];
    float sum = v0+v1+v2;
    float sq  = v0*v0+v1*v1+v2*v2;
    float ws1 = waveSum(sum), ws2 = waveSum(sq);
    __shared__ float red[4];
    int w = t>>6, lane = t&63;
    if (lane == 0){ red[w] = ws1; red[w+2] = ws2; }
    __syncthreads();
    float mu   = (red[0]+red[1]) * (1.f/CS);
    float var  = (red[2]+red[3]) * (1.f/CS) - mu*mu;
    float rstd = rsqrtf(var + 1e-5f);
    float* o = s + (size_t)i*CS;
    o[t]     = (v0-mu)*rstd*g[t]     + b[t];
    o[t+128] = (v1-mu)*rstd*g[t+128] + b[t+128];
    o[t+256] = (v2-mu)*rstd*g[t+256] + b[t+256];
    return;
  }
  int idx = (blk - LSEQ)*128 + t;
  if (idx < PROJW){
    float bv = 0.f;
    if (idx >= 1440)      bv = bvp[idx-1440];
    else if (idx >= 1296) bv = bkp[idx-1296];
    else if (idx >= 1152) bv = bqp[idx-1152];
    bcat[idx] = bv;
  }
  if (idx >= 384*PROJW) return;
  int r = idx / PROJW, c = idx % PROJW;
  float v;
  if (c < 384)       v = Wq[r*384 + c];
  else if (c < 768)  v = Wk[r*384 + c-384];
  else if (c < 1152) v = Wv[r*384 + c-768];
  else if (c < 1296) v = Wqp[r*144 + c-1152];
  else if (c < 1440) v = Wkp[r*144 + c-1296];
  else               v = Wvp[r*288 + c-1440];
  wcat[idx] = v;
}

// ---------------- generic tiled GEMM (64x64, BK=16), aligned LDS, optional split-K ----------------
__global__ __launch_bounds__(256) void k_gemm(
    const float* __restrict__ A, const float* __restrict__ B,
    const float* __restrict__ bias, float* __restrict__ C,
    int M, int N, int K, int kChunk){
  __shared__ float As[16][68];   // 68 floats = 272 B = 17x16 -> f4-aligned rows
  __shared__ float Bs[16][68];
  int j0 = blockIdx.x*64, i0 = blockIdx.y*64;
  int kBeg = blockIdx.z * kChunk;
  int t = threadIdx.x, tx = t & 15, ty = t >> 4;
  int arow = t >> 2, ak = (t & 3) * 4;
  int brow = t >> 4, bcol = (t & 15) * 4;
  float acc[4][4] = {};
  for (int kb = kBeg; kb < kBeg + kChunk; kb += 16){
    float4 av = *(const float4*)(A + (size_t)(i0+arow)*K + kb + ak);
    As[ak+0][arow]=av.x; As[ak+1][arow]=av.y; As[ak+2][arow]=av.z; As[ak+3][arow]=av.w;
    float4 bv = make_float4(0.f,0.f,0.f,0.f);
    if (j0 + bcol < N) bv = *(const float4*)(B + (size_t)(kb+brow)*N + j0 + bcol);
    *(float4*)(&Bs[brow][bcol]) = bv;
    __syncthreads();
#pragma unroll
    for (int kk = 0; kk < 16; ++kk){
      float a[4], b[4];
      *(float4*)a = *(const float4*)(&As[kk][ty*4]);
      *(float4*)b = *(const float4*)(&Bs[kk][tx*4]);
#pragma unroll
      for (int r = 0; r < 4; ++r)
#pragma unroll
        for (int c = 0; c < 4; ++c) acc[r][c] += a[r]*b[c];
    }
    __syncthreads();
  }
  bool noSplit = (gridDim.z == 1);
  float* Cz = C + (size_t)blockIdx.z * M * N;
#pragma unroll
  for (int r = 0; r < 4; ++r){
    int i = i0 + ty*4 + r;
#pragma unroll
    for (int c = 0; c < 4; ++c){
      int j = j0 + tx*4 + c;
      if (j < N){
        float v = acc[r][c];
        if (noSplit && bias) v += bias[j];
        Cz[(size_t)i*N + j] = v;
      }
    }
  }
}

// ---------------- prep: frames + Qa/Ka (K=44 pad 48) + norm biases ----------------
__global__ __launch_bounds__(256) void k_prep(
    float* __restrict__ proj, const float* __restrict__ rots,
    const float* __restrict__ trans, const float* __restrict__ hw,
    float* __restrict__ Qa, float* __restrict__ Ka, float* __restrict__ nrm){
  int i = blockIdx.x, t = threadIdx.x;
  __shared__ float wcl[12];
  __shared__ float qg[144], kg[144];
  if (t < 12) wcl[t] = log1pf(__expf(hw[t]));
  float* prow = proj + (size_t)i*PROJW;
  if (t < 192){
    const float* R  = rots + i*9;
    const float* tr = trans + i*3;
    int off = (t < 48) ? (1152 + t*3) : ((t < 96) ? (1296 + (t-48)*3) : (1440 + (t-96)*3));
    float x = prow[off], y = prow[off+1], z = prow[off+2];
    float gx = R[0]*x + R[1]*y + R[2]*z + tr[0];
    float gy = R[3]*x + R[4]*y + R[5]*z + tr[1];
    float gz = R[6]*x + R[7]*y + R[8]*z + tr[2];
    if (t < 48){ qg[t*3]=gx; qg[t*3+1]=gy; qg[t*3+2]=gz; }
    else if (t < 96){ int u=t-48; kg[u*3]=gx; kg[u*3+1]=gy; kg[u*3+2]=gz; }
    else { prow[off]=gx; prow[off+1]=gy; prow[off+2]=gz; }  // v_g in place
  }
  __syncthreads();
  const float isq = 0.17677669529663687f;
  for (int idx = t; idx < 576; idx += 256){
    int h = idx/48, d = idx%48;
    float qv = 0.f, kv = 0.f;
    if (d < 32){ qv = prow[h*32 + d]*isq; kv = prow[384 + h*32 + d]; }
    else if (d < 44){ qv = qg[h*12 + (d-32)]*wcl[h]; kv = kg[h*12 + (d-32)]; }
    Qa[((size_t)h*LSEQ + i)*48 + d] = qv;
    Ka[((size_t)h*LSEQ + i)*48 + d] = kv;
  }
  if (t < 24){
    int h = t % 12; int isK = (t >= 12) ? 1 : 0;
    const float* g = isK ? kg : qg;
    float sum = 0.f;
#pragma unroll
    for (int d = 0; d < 12; ++d){ float v = g[h*12+d]; sum += v*v; }
    nrm[((size_t)(isK*12 + h))*LSEQ + i] = -0.5f*wcl[h]*sum;
  }
}

// ---------------- logits GEMM -> attn[i][h][j]; transposed LDS, b128 reads ----------------
__global__ __launch_bounds__(256) void k_qkaug(
    const float* __restrict__ Qa, const float* __restrict__ Ka,
    const float* __restrict__ nrm, float* __restrict__ logits){
  int j0 = blockIdx.x*64, i0 = blockIdx.y*64, h = blockIdx.z;
  __shared__ float Qs[48][68], Ks[48][68];  // [k][row], 68-pad -> aligned f4 rows
  __shared__ float nq[64], nk[64];
  int t = threadIdx.x;
  for (int idx = t; idx < 768; idx += 256){
    int row = idx/12, c4 = (idx%12)*4;
    float4 qv = *(const float4*)(Qa + ((size_t)h*LSEQ + i0+row)*48 + c4);
    Qs[c4+0][row]=qv.x; Qs[c4+1][row]=qv.y; Qs[c4+2][row]=qv.z; Qs[c4+3][row]=qv.w;
    float4 kv = *(const float4*)(Ka + ((size_t)h*LSEQ + j0+row)*48 + c4);
    Ks[c4+0][row]=kv.x; Ks[c4+1][row]=kv.y; Ks[c4+2][row]=kv.z; Ks[c4+3][row]=kv.w;
  }
  if (t < 64) nq[t] = nrm[(size_t)h*LSEQ + i0 + t];
  else if (t < 128) nk[t-64] = nrm[(size_t)(12+h)*LSEQ + j0 + (t-64)];
  __syncthreads();
  int tx = t & 15, ty = t >> 4;
  float acc[4][4] = {};
#pragma unroll 4
  for (int k = 0; k < 44; ++k){
    float a[4], b[4];
    *(float4*)a = *(const float4*)(&Qs[k][ty*4]);
    *(float4*)b = *(const float4*)(&Ks[k][tx*4]);
#pragma unroll
    for (int r = 0; r < 4; ++r)
#pragma unroll
      for (int c = 0; c < 4; ++c) acc[r][c] += a[r]*b[c];
  }
  float nqa[4] = {nq[ty*4], nq[ty*4+1], nq[ty*4+2], nq[ty*4+3]};
  float nk0=nk[tx*4], nk1=nk[tx*4+1], nk2=nk[tx*4+2], nk3=nk[tx*4+3];
#pragma unroll
  for (int r = 0; r < 4; ++r){
    float4 o = make_float4(acc[r][0]+nqa[r]+nk0, acc[r][1]+nqa[r]+nk1,
                           acc[r][2]+nqa[r]+nk2, acc[r][3]+nqa[r]+nk3);
    *(float4*)(logits + ((size_t)(i0+ty*4+r)*NH + h)*LSEQ + j0 + tx*4) = o;
  }
}

// ---------------- fused: pairbias -> softmax -> out_pair; block per i (R15 exact) ----------------
__global__ __launch_bounds__(768) void k_pairfused(
    const float* __restrict__ pair, const float* __restrict__ Wpb,
    float* __restrict__ attn,   // [i][h][j]: logits in -> normalized probs out
    float* __restrict__ cat){
  const int i = blockIdx.x, t = threadIdx.x;          // t in [0,768)
  __shared__ __align__(16) float Sb[12*776];          // bias -> probs -> epilogue red
  const float4* prowf4 = (const float4*)(pair + (size_t)i*LSEQ*CZ);
  const int w = t >> 6, lane = t & 63;                // 12 waves

  // ===== phase 1: pairbias; thread t = row t =====
  {
    const float4* src = prowf4 + (size_t)t*32;
    float acc[12] = {0.f,0.f,0.f,0.f,0.f,0.f,0.f,0.f,0.f,0.f,0.f,0.f};
#pragma unroll 2
    for (int c4 = 0; c4 < 32; ++c4){
      float4 pv = src[c4];
      const float* wq = Wpb + c4*48;   // wave-uniform -> scalar loads
#pragma unroll
      for (int h = 0; h < 12; ++h)
        acc[h] += pv.x*wq[h] + pv.y*wq[h+12] + pv.z*wq[h+24] + pv.w*wq[h+36];
    }
#pragma unroll
    for (int h = 0; h < 12; ++h) Sb[h*776 + t] = acc[h];
  }
  __syncthreads();

  // ===== phase 2: softmax; wave w handles head w =====
  {
    const int h = w;
    float* lg = attn + ((size_t)i*NH + h)*LSEQ;
    float4 xa = *(const float4*)(lg + lane*4);
    float4 xb = *(const float4*)(lg + 256 + lane*4);
    float4 xc = *(const float4*)(lg + 512 + lane*4);
    float4 ba = *(const float4*)(Sb + h*776 + lane*4);
    float4 bb = *(const float4*)(Sb + h*776 + 256 + lane*4);
    float4 bc = *(const float4*)(Sb + h*776 + 512 + lane*4);
    xa.x+=ba.x; xa.y+=ba.y; xa.z+=ba.z; xa.w+=ba.w;
    xb.x+=bb.x; xb.y+=bb.y; xb.z+=bb.z; xb.w+=bb.w;
    xc.x+=bc.x; xc.y+=bc.y; xc.z+=bc.z; xc.w+=bc.w;
    float m = fmaxf(fmaxf(fmaxf(xa.x,xa.y),fmaxf(xa.z,xa.w)),
             fmaxf(fmaxf(fmaxf(xb.x,xb.y),fmaxf(xb.z,xb.w)),
                   fmaxf(fmaxf(xc.x,xc.y),fmaxf(xc.z,xc.w))));
#pragma unroll
    for (int ms = 32; ms > 0; ms >>= 1) m = fmaxf(m, __shfl_xor(m, ms));
    xa.x=__expf(xa.x-m); xa.y=__expf(xa.y-m); xa.z=__expf(xa.z-m); xa.w=__expf(xa.w-m);
    xb.x=__expf(xb.x-m); xb.y=__expf(xb.y-m); xb.z=__expf(xb.z-m); xb.w=__expf(xb.w-m);
    xc.x=__expf(xc.x-m); xc.y=__expf(xc.y-m); xc.z=__expf(xc.z-m); xc.w=__expf(xc.w-m);
    float sm = xa.x+xa.y+xa.z+xa.w + xb.x+xb.y+xb.z+xb.w + xc.x+xc.y+xc.z+xc.w;
#pragma unroll
    for (int ms = 32; ms > 0; ms >>= 1) sm += __shfl_xor(sm, ms);
    float inv = 1.f/sm;
    xa.x*=inv; xa.y*=inv; xa.z*=inv; xa.w*=inv;
    xb.x*=inv; xb.y*=inv; xb.z*=inv; xb.w*=inv;
    xc.x*=inv; xc.y*=inv; xc.z*=inv; xc.w*=inv;
    *(float4*)(Sb + h*776 + lane*4)       = xa;
    *(float4*)(Sb + h*776 + 256 + lane*4) = xb;
    *(float4*)(Sb + h*776 + 512 + lane*4) = xc;
    *(float4*)(lg + lane*4)       = xa;
    *(float4*)(lg + 256 + lane*4) = xb;
    *(float4*)(lg + 512 + lane*4) = xc;
  }
  __syncthreads();

  // ===== phase 3: out_pair; 32 ch-quads x 24 row-groups =====
  const int cq = t & 31, rp = t >> 5;   // rp in [0,24)
  float4 acc3[12];
#pragma unroll
  for (int h = 0; h < 12; ++h) acc3[h] = make_float4(0.f,0.f,0.f,0.f);
#pragma unroll 2
  for (int g = 0; g < 8; ++g){
    const int r0 = g*96 + rp*4;
    float4 pv0 = prowf4[(size_t)(r0+0)*32 + cq];
    float4 pv1 = prowf4[(size_t)(r0+1)*32 + cq];
    float4 pv2 = prowf4[(size_t)(r0+2)*32 + cq];
    float4 pv3 = prowf4[(size_t)(r0+3)*32 + cq];
#pragma unroll
    for (int h = 0; h < 12; ++h){
      float4 p4 = *(const float4*)(Sb + h*776 + r0);
      acc3[h].x += pv0.x*p4.x + pv1.x*p4.y + pv2.x*p4.z + pv3.x*p4.w;
      acc3[h].y += pv0.y*p4.x + pv1.y*p4.y + pv2.y*p4.z + pv3.y*p4.w;
      acc3[h].z += pv0.z*p4.x + pv1.z*p4.y + pv2.z*p4.z + pv3.z*p4.w;
      acc3[h].w += pv0.w*p4.x + pv1.w*p4.y + pv2.w*p4.z + pv3.w*p4.w;
    }
  }
#pragma unroll
  for (int h = 0; h < 12; ++h){
    acc3[h].x += __shfl_xor(acc3[h].x, 32);
    acc3[h].y += __shfl_xor(acc3[h].y, 32);
    acc3[h].z += __shfl_xor(acc3[h].z, 32);
    acc3[h].w += __shfl_xor(acc3[h].w, 32);
  }
  __syncthreads();   // probs dead; reuse Sb[0..9216) as red[6][1536]
  if (w < 6 && lane < 32){
#pragma unroll
    for (int h = 0; h < 12; ++h)
      *(float4*)(Sb + w*1536 + h*128 + cq*4) = acc3[h];
  }
  __syncthreads();
  if (w >= 6 && lane < 32){
#pragma unroll
    for (int h = 0; h < 12; ++h){
      float4* d = (float4*)(Sb + (w-6)*1536 + h*128 + cq*4);
      float4 v = *d;
      v.x += acc3[h].x; v.y += acc3[h].y; v.z += acc3[h].z; v.w += acc3[h].w;
      *d = v;
    }
  }
  __syncthreads();
  float* crow = cat + (size_t)i*OUTD + 672;
#pragma unroll
  for (int o = t; o < 1536; o += 768)
    crow[o] = Sb[o] + Sb[1536+o] + Sb[3072+o] + Sb[4608+o] + Sb[6144+o] + Sb[7680+o];
}

// ---------------- PV GEMM (16-row tiles) + fused out-pts rotation ----------------
__global__ __launch_bounds__(256) void k_pv(
    const float* __restrict__ attn, const float* __restrict__ proj,
    const float* __restrict__ rots, const float* __restrict__ trans,
    float* __restrict__ cat){
  int h = blockIdx.y, i0 = blockIdx.x*16;
  __shared__ float As[32][17];   // [kk][row]
  __shared__ float Bs[32][60];   // 60 floats = 240 B = 15x16 -> f4-aligned rows
  __shared__ float pts[16][24];
  int t = threadIdx.x, tx = t & 15, ty = t >> 4;
  float acc[4] = {};
  for (int kb = 0; kb < LSEQ; kb += 32){
    __syncthreads();
    {
      int row = t >> 4, k2 = (t & 15)*2;
      float2 av = *(const float2*)(attn + ((size_t)(i0+row)*NH + h)*LSEQ + kb + k2);
      As[k2][row] = av.x; As[k2+1][row] = av.y;
    }
    for (int idx = t; idx < 32*56; idx += 256){
      int kk = idx/56, n = idx%56;
      const float* prow = proj + (size_t)(kb+kk)*PROJW;
      Bs[kk][n] = (n < 32) ? prow[768 + h*32 + n] : prow[1440 + h*24 + (n-32)];
    }
    __syncthreads();
    if (tx < 14){
#pragma unroll
      for (int kk = 0; kk < 32; ++kk){
        float a = As[kk][ty];
        float b[4]; *(float4*)b = *(const float4*)(&Bs[kk][tx*4]);
        acc[0] += a*b[0]; acc[1] += a*b[1]; acc[2] += a*b[2]; acc[3] += a*b[3];
      }
    }
  }
  __syncthreads();
  if (tx < 14){
    int i = i0 + ty;
#pragma unroll
    for (int c = 0; c < 4; ++c){
      int n = tx*4 + c;
      if (n < 32) cat[(size_t)i*OUTD + h*32 + n] = acc[c];
      else pts[ty][n-32] = acc[c];
    }
  }
  __syncthreads();
  if (t < 128){
    int row = t >> 3, p = t & 7;
    int i = i0 + row;
    const float* R = rots + i*9; const float* tr = trans + i*3;
    float x = pts[row][p*3]   - tr[0];
    float y = pts[row][p*3+1] - tr[1];
    float z = pts[row][p*3+2] - tr[2];
    float* o = cat + (size_t)i*OUTD + 384 + h*24 + p*3;
    o[0] = R[0]*x + R[3]*y + R[6]*z;
    o[1] = R[1]*x + R[4]*y + R[7]*z;
    o[2] = R[2]*x + R[5]*y + R[8]*z;
  }
}

// ---------------- split-K reduce + bias (6 partials) ----------------
__global__ __launch_bounds__(256) void k_reduce(
    const float* __restrict__ part, const float* __restrict__ bias,
    float* __restrict__ out){
  int idx = blockIdx.x*256 + threadIdx.x;
  if (idx >= LSEQ*CS) return;
  float v = bias[idx % CS];
#pragma unroll
  for (int z = 0; z < 6; ++z) v += part[(size_t)z*LSEQ*CS + idx];
  out[idx] = v;
}

extern "C" void kernel_launch(void* const* d_in, const int* in_sizes, int n_in,
                              void* d_out, int out_size, void* d_ws, size_t ws_size,
                              hipStream_t stream){
  const float* single = (const float*)d_in[0];
  const float* pair   = (const float*)d_in[1];
  const float* rots   = (const float*)d_in[2];
  const float* trans  = (const float*)d_in[3];
  const float* ln_g   = (const float*)d_in[4];
  const float* ln_b   = (const float*)d_in[5];
  const float* Wq  = (const float*)d_in[6];
  const float* Wk  = (const float*)d_in[7];
  const float* Wv  = (const float*)d_in[8];
  const float* Wqp = (const float*)d_in[9];
  const float* bqp = (const float*)d_in[10];
  const float* Wkp = (const float*)d_in[11];
  const float* bkp = (const float*)d_in[12];
  const float* Wvp = (const float*)d_in[13];
  const float* bvp = (const float*)d_in[14];
  const float* Wpb = (const float*)d_in[15];
  const float* hw  = (const float*)d_in[16];
  const float* Wo  = (const float*)d_in[17];
  const float* bo  = (const float*)d_in[18];
  float* out = (float*)d_out;

  float* ws = (float*)d_ws;
  float* s    = ws;                  // 294912
  float* wcat = ws + 294912;         // 663552
  float* bcat = ws + 958464;         // 1792
  float* Qa   = ws;                  // overlays s/wcat after proj GEMM
  float* Ka   = ws + 442368;
  float* nrm  = ws + 884736;
  float* proj = ws + 960256;         // 1327104
  float* attn = ws + 2287360;        // 7077888 [i][h][j] (logits -> probs in place)
  float* cat  = ws + 9365248;        // 1695744
  float* part = attn;                // 6*294912 = 1769472 (attn dead after pv)

  int wcatBlocks = (384*PROJW + 127)/128;
  k_lnwcat<<<LSEQ + wcatBlocks, 128, 0, stream>>>(single, ln_g, ln_b, s,
      Wq, Wk, Wv, Wqp, Wkp, Wvp, bqp, bkp, bvp, wcat, bcat);
  k_gemm<<<dim3(27,12,1), 256, 0, stream>>>(s, wcat, bcat, proj, 768, PROJW, 384, 384);
  k_prep<<<LSEQ, 256, 0, stream>>>(proj, rots, trans, hw, Qa, Ka, nrm);
  k_qkaug<<<dim3(12,12,12), 256, 0, stream>>>(Qa, Ka, nrm, attn);
  k_pairfused<<<LSEQ, 768, 0, stream>>>(pair, Wpb, attn, cat);
  k_pv<<<dim3(48, NH), 256, 0, stream>>>(attn, proj, rots, trans, cat);
  k_gemm<<<dim3(6,12,6), 256, 0, stream>>>(cat, Wo, nullptr, part, 768, CS, OUTD, 368);
  k_reduce<<<(LSEQ*CS+255)/256, 256, 0, stream>>>(part, bo, out);
}